// Round 14
// baseline (210.383 us; speedup 1.0000x reference)
//
#include <hip/hip_runtime.h>

typedef unsigned int uint;
typedef __attribute__((ext_vector_type(8))) short short8;
typedef __attribute__((ext_vector_type(4))) float f32x4;

#define NBUCK 512
#define BCAP  4608          // packed per-bucket capacity (mean 4096 + 8 sigma)
#define CCAP  5632          // csr per-bucket capacity (BCAP + align pad slack)
#define NPB   512           // partition blocks
#define PCHUNK 4096         // edges per partition block

// ---------------- bf16 helpers ----------------

__device__ __forceinline__ uint pack_bf2(float a, float b) {
    uint ua = __float_as_uint(a), ub = __float_as_uint(b);
    ua = (ua + 0x7FFFu + ((ua >> 16) & 1u)) >> 16;        // RNE to bf16
    ub = (ub + 0x7FFFu + ((ub >> 16) & 1u)) >> 16;
    return ua | (ub << 16);
}
__device__ __forceinline__ float bf_lo(uint u) { return __uint_as_float(u << 16); }
__device__ __forceinline__ float bf_hi(uint u) { return __uint_as_float(u & 0xFFFF0000u); }

// ---------------- K1: hist | cvtA | cvtB | precompute | zero(out,cnt) ----------------

#define HIST_BLOCKS NPB
#define CVTA_BLOCKS 3072
#define CVTB_BLOCKS 192

__global__ __launch_bounds__(256) void k1_fused(const int* __restrict__ dst,
                                                int* __restrict__ H, int E,
                                                const float2* __restrict__ smiles2,
                                                uint* __restrict__ Abf, int n2,
                                                const float* __restrict__ emb_W1,
                                                uint* __restrict__ Btbf,
                                                const float* __restrict__ fc1_W,
                                                const float* __restrict__ fc1_b,
                                                const float* __restrict__ fcf_W,
                                                const float* __restrict__ fcf_b,
                                                const float* __restrict__ gcn_fc_W,
                                                const float* __restrict__ gcn_fc_b,
                                                const float* __restrict__ conv2_W,
                                                const float* __restrict__ conv2_b,
                                                const float* __restrict__ emb_W2,
                                                const float* __restrict__ emb_b2,
                                                float* __restrict__ vv,
                                                float* __restrict__ uu,
                                                float* __restrict__ Cc,
                                                float* __restrict__ cnt,
                                                float* __restrict__ out, int B) {
    __shared__ float shbuf[64 * 66];
    int tid = threadIdx.x;
    int bid = blockIdx.x;
    if (bid < HIST_BLOCKS) {
        int* lh = (int*)shbuf;
        int e0 = bid * PCHUNK, e1 = min(e0 + PCHUNK, E);
        lh[tid] = 0; lh[tid + 256] = 0;
        __syncthreads();
        for (int e = e0 + tid; e < e1; e += 256)
            atomicAdd(&lh[dst[e] >> 8], 1);
        __syncthreads();
        H[bid * NBUCK + tid] = lh[tid];
        H[bid * NBUCK + tid + 256] = lh[tid + 256];
    } else if (bid < HIST_BLOCKS + CVTA_BLOCKS) {
        int i = (bid - HIST_BLOCKS) * 512 + tid;
        if (i < n2) { float2 vx = smiles2[i]; Abf[i] = pack_bf2(vx.x, vx.y); }
        i += 256;
        if (i < n2) { float2 vx = smiles2[i]; Abf[i] = pack_bf2(vx.x, vx.y); }
    } else if (bid < HIST_BLOCKS + CVTA_BLOCKS + CVTB_BLOCKS) {
        int bb = bid - HIST_BLOCKS - CVTA_BLOCKS;
        int k0 = (bb % 12) * 64, n0 = (bb / 12) * 64;
        float (*t)[65] = (float(*)[65])shbuf;
        int r = tid >> 2, cg = (tid & 3) * 16;
#pragma unroll
        for (int i = 0; i < 16; i++)
            t[r][cg + i] = emb_W1[(size_t)(k0 + r) * 1024 + n0 + cg + i];
        __syncthreads();
        int n = tid >> 2;
#pragma unroll
        for (int i = 0; i < 8; i++) {
            int u = (tid & 3) * 8 + i;
            Btbf[(size_t)(n0 + n) * 384 + (k0 >> 1) + u] = pack_bf2(t[2 * u][n], t[2 * u + 1][n]);
        }
    } else if (bid == HIST_BLOCKS + CVTA_BLOCKS + CVTB_BLOCKS) {
        float* t1s = shbuf;
        float* t2s = shbuf + 128;
        if (tid < 128) {
            float s = 0;
            for (int j = 0; j < 64; j++) s += fc1_W[tid * 64 + j] * fcf_W[j];
            t1s[tid] = s;
        }
        __syncthreads();
        if (tid < 128) {
            float s = 0;
            for (int m = 0; m < 64; m++) s += gcn_fc_W[tid * 64 + m] * t1s[64 + m];
            t2s[tid] = s;
        }
        __syncthreads();
        if (tid < 64) {
            float s = 0;
            for (int p = 0; p < 128; p++) s += conv2_W[tid * 128 + p] * t2s[p];
            vv[tid] = s;
        }
        for (int jj = tid; jj < 1024; jj += 256) {
            float s = 0;
            for (int k = 0; k < 64; k++) s += emb_W2[jj * 64 + k] * t1s[k];
            uu[jj] = s;
        }
        if (tid == 0) {
            float c = fcf_b[0];
            for (int j = 0; j < 64; j++)  c += fc1_b[j] * fcf_W[j];
            for (int k = 0; k < 64; k++)  c += emb_b2[k] * t1s[k];
            for (int p = 0; p < 128; p++) c += conv2_b[p] * t2s[p];
            for (int m = 0; m < 64; m++)  c += gcn_fc_b[m] * t1s[64 + m];
            Cc[0] = c;
        }
    } else {
        int i = (bid - HIST_BLOCKS - CVTA_BLOCKS - CVTB_BLOCKS - 1) * 256 + tid;
        if (i < B) { cnt[i] = 0.f; out[i] = 0.f; }
    }
}

// ---------------- K2: column exclusive scan -> bases ----------------

__global__ __launch_bounds__(256) void kp_base(int* __restrict__ H, int* __restrict__ bcur) {
    __shared__ int lsum[256];
    int tid = threadIdx.x, b = blockIdx.x;
    int v0 = H[(tid * 2 + 0) * NBUCK + b];
    int v1 = H[(tid * 2 + 1) * NBUCK + b];
    int s = v0 + v1;
    lsum[tid] = s;
    for (int d = 1; d < 256; d <<= 1) {
        __syncthreads();
        int t = (tid >= d) ? lsum[tid - d] : 0;
        __syncthreads();
        lsum[tid] += t;
    }
    int run = b * BCAP + (lsum[tid] - s);
    H[(tid * 2 + 0) * NBUCK + b] = run; run += v0;
    H[(tid * 2 + 1) * NBUCK + b] = run; run += v1;
    if (tid == 255) bcur[b] = lsum[255];    // total edges in bucket
}

// ---------------- K3: ranked scatter (BW) || embedding MFMA GEMM (reg-prefetch pipeline) ----------------

#define EMB_BLOCKS 256

__global__ __launch_bounds__(256) void k_scatter_emb(const int* __restrict__ src,
                                                     const int* __restrict__ dst,
                                                     const int* __restrict__ H,
                                                     uint* __restrict__ packed, int E,
                                                     const uint* __restrict__ Abf,
                                                     const uint* __restrict__ Btbf,
                                                     const float* __restrict__ b1,
                                                     const float* __restrict__ uu,
                                                     float* __restrict__ out) {
    __shared__ uint4 shu[2048];     // 32 KB union
    int tid = threadIdx.x;
    int bid = blockIdx.x;
    if (bid < NPB) {
        int* lbase = (int*)shu;
        int* lh = lbase + NBUCK;
        int e0 = bid * PCHUNK, e1 = min(e0 + PCHUNK, E);
        lbase[tid] = H[bid * NBUCK + tid];
        lbase[tid + 256] = H[bid * NBUCK + tid + 256];
        lh[tid] = 0; lh[tid + 256] = 0;
        __syncthreads();
        for (int e = e0 + tid; e < e1; e += 256) {
            int s = src[e], d = dst[e];
            int b = d >> 8;
            int r = atomicAdd(&lh[b], 1);
            int pos = lbase[b] + r;
            if (pos < (b + 1) * BCAP)
                packed[pos] = ((uint)s << 8) | (uint)(d & 255);
        }
    } else {
        int eb = bid - NPB;
        int r0 = (eb & 31) * 128, n0 = (eb >> 5) * 128;
        uint4 (*As)[8] = (uint4(*)[8])shu;
        uint4 (*Bs)[8] = (uint4(*)[8])(shu + 1024);
        int wave = tid >> 6, lane = tid & 63;
        int wm = wave & 1, wn = wave >> 1;
        f32x4 acc[4][4] = {};

        int rowi[4], ci[4];
        uint4 ra[4], rb[4];
#pragma unroll
        for (int i = 0; i < 4; i++) {
            int idx = tid * 4 + i;
            rowi[i] = idx >> 3;
            ci[i] = idx & 7;
        }
        // prologue: tile 0 -> regs -> LDS
#pragma unroll
        for (int i = 0; i < 4; i++) {
            ra[i] = *(const uint4*)&Abf[(size_t)(r0 + rowi[i]) * 384 + ci[i] * 4];
            rb[i] = *(const uint4*)&Btbf[(size_t)(n0 + rowi[i]) * 384 + ci[i] * 4];
        }
#pragma unroll
        for (int i = 0; i < 4; i++) {
            As[rowi[i]][ci[i] ^ (rowi[i] & 7)] = ra[i];
            Bs[rowi[i]][ci[i] ^ (rowi[i] & 7)] = rb[i];
        }
        __syncthreads();

        for (int kt = 0; kt < 12; kt++) {
            if (kt < 11) {      // prefetch next tile into regs; flies during MFMA
                int ko = (kt + 1) * 32;
#pragma unroll
                for (int i = 0; i < 4; i++) {
                    ra[i] = *(const uint4*)&Abf[(size_t)(r0 + rowi[i]) * 384 + ko + ci[i] * 4];
                    rb[i] = *(const uint4*)&Btbf[(size_t)(n0 + rowi[i]) * 384 + ko + ci[i] * 4];
                }
            }
            int lr = lane & 15, kg = lane >> 4;
#pragma unroll
            for (int kk = 0; kk < 2; kk++) {
                short8 af[4], bfr[4];
#pragma unroll
                for (int m = 0; m < 4; m++) {
                    int row = wm * 64 + m * 16 + lr;
                    af[m] = *(short8*)&As[row][(kk * 4 + kg) ^ (row & 7)];
                }
#pragma unroll
                for (int n = 0; n < 4; n++) {
                    int col = wn * 64 + n * 16 + lr;
                    bfr[n] = *(short8*)&Bs[col][(kk * 4 + kg) ^ (col & 7)];
                }
#pragma unroll
                for (int m = 0; m < 4; m++)
#pragma unroll
                    for (int n = 0; n < 4; n++)
                        acc[m][n] = __builtin_amdgcn_mfma_f32_16x16x32_bf16(af[m], bfr[n], acc[m][n], 0, 0, 0);
            }
            __syncthreads();
            if (kt < 11) {
#pragma unroll
                for (int i = 0; i < 4; i++) {
                    As[rowi[i]][ci[i] ^ (rowi[i] & 7)] = ra[i];
                    Bs[rowi[i]][ci[i] ^ (rowi[i] & 7)] = rb[i];
                }
                __syncthreads();
            }
        }

        int lr = lane & 15, lq = lane >> 4;
#pragma unroll
        for (int m = 0; m < 4; m++) {
#pragma unroll
            for (int j = 0; j < 4; j++) {
                int row = r0 + wm * 64 + m * 16 + lq * 4 + j;
                float p = 0.f;
#pragma unroll
                for (int n = 0; n < 4; n++) {
                    int col = n0 + wn * 64 + n * 16 + lr;
                    p += fmaxf(acc[m][n][j] + b1[col], 0.f) * uu[col];
                }
                p += __shfl_xor(p, 1);
                p += __shfl_xor(p, 2);
                p += __shfl_xor(p, 4);
                p += __shfl_xor(p, 8);
                if (lr == 0) atomicAdd(&out[row], p);
            }
        }
    }
}

// ---------------- K4: per-bucket sort -> CSR, then y' gemm for the bucket's 256 rows ----------------

__global__ __launch_bounds__(256) void k_build_gemm(const uint* __restrict__ packed,
                                                    const int* __restrict__ bcur,
                                                    const int* __restrict__ batch,
                                                    int* __restrict__ degi,
                                                    float* __restrict__ dinv,
                                                    int* __restrict__ off,
                                                    int* __restrict__ csr_s,
                                                    float* __restrict__ cnt,
                                                    const float* __restrict__ A,
                                                    const float* __restrict__ W,
                                                    uint* __restrict__ ybf) {
    __shared__ int lh[256];
    __shared__ int lscan[256];
    __shared__ int loff[256];
    __shared__ float ldinv[256];
    __shared__ float Ws[64][64];
    __shared__ float As[64][65];
    int tid = threadIdx.x, b = blockIdx.x;
    int cntE = min(bcur[b], BCAP);
    const uint* pk = packed + (size_t)b * BCAP;

    // ---- phase 1: counting sort (single read, rank capture) ----
    uint reg[18];
    ushort rk[18];
    lh[tid] = 0;
    __syncthreads();
#pragma unroll
    for (int t = 0; t < 18; t++) {
        int idx = t * 256 + tid;
        if (idx < cntE) {
            uint u = pk[idx];
            reg[t] = u;
            rk[t] = (ushort)atomicAdd(&lh[u & 255u], 1);
        }
    }
    __syncthreads();
    int dg = lh[tid];
    int dgp = (dg + 3) & ~3;          // pad to int4 alignment
    lscan[tid] = dgp;
    for (int d = 1; d < 256; d <<= 1) {
        __syncthreads();
        int t = (tid >= d) ? lscan[tid - d] : 0;
        __syncthreads();
        lscan[tid] += t;
    }
    int excl = lscan[tid] - dgp;
    int node = (b << 8) + tid;
    float dv = rsqrtf((float)dg + 1.0f);
    degi[node] = dg;
    dinv[node] = dv;
    ldinv[tid] = dv;
    off[node] = b * CCAP + excl;
    loff[tid] = excl;
    atomicAdd(&cnt[batch[node]], 1.0f);
    __syncthreads();
    int base = b * CCAP;
#pragma unroll
    for (int t = 0; t < 18; t++) {
        int idx = t * 256 + tid;
        if (idx < cntE) {
            uint u = reg[t];
            csr_s[base + loff[u & 255u] + rk[t]] = (int)(u >> 8);
        }
    }

    // ---- phase 2: y' = dinv * (x @ W1) for the bucket's 256 rows (4 tiles of 64) ----
    {
        const float4* W4 = (const float4*)W;
#pragma unroll
        for (int i = 0; i < 4; i++) {
            int idx = tid + 256 * i;
            float4 w = W4[idx];
            int k = idx >> 4, c = (idx & 15) * 4;
            *(float4*)&Ws[k][c] = w;
        }
    }
    int ty = tid >> 4, tx = tid & 15;
    for (int t = 0; t < 4; t++) {
        int r0 = (b << 8) + t * 64;
        __syncthreads();
        {
            int r = tid >> 2, cg = tid & 3;
            const float4* A4 = (const float4*)(A + (size_t)(r0 + r) * 64);
#pragma unroll
            for (int i = 0; i < 4; i++) {
                float4 a = A4[cg + 4 * i];
                int c = (cg + 4 * i) * 4;
                As[r][c + 0] = a.x; As[r][c + 1] = a.y; As[r][c + 2] = a.z; As[r][c + 3] = a.w;
            }
        }
        __syncthreads();
        float acc[4][4] = {};
#pragma unroll 16
        for (int kk = 0; kk < 64; kk++) {
            float4 wv = *(const float4*)&Ws[kk][tx * 4];
            float a0 = As[ty * 4 + 0][kk];
            float a1 = As[ty * 4 + 1][kk];
            float a2 = As[ty * 4 + 2][kk];
            float a3 = As[ty * 4 + 3][kk];
            acc[0][0] += a0 * wv.x; acc[0][1] += a0 * wv.y; acc[0][2] += a0 * wv.z; acc[0][3] += a0 * wv.w;
            acc[1][0] += a1 * wv.x; acc[1][1] += a1 * wv.y; acc[1][2] += a1 * wv.z; acc[1][3] += a1 * wv.w;
            acc[2][0] += a2 * wv.x; acc[2][1] += a2 * wv.y; acc[2][2] += a2 * wv.z; acc[2][3] += a2 * wv.w;
            acc[3][0] += a3 * wv.x; acc[3][1] += a3 * wv.y; acc[3][2] += a3 * wv.z; acc[3][3] += a3 * wv.w;
        }
#pragma unroll
        for (int i = 0; i < 4; i++) {
            float wsc = ldinv[t * 64 + ty * 4 + i];
            uint2 o;
            o.x = pack_bf2(wsc * acc[i][0], wsc * acc[i][1]);
            o.y = pack_bf2(wsc * acc[i][2], wsc * acc[i][3]);
            *(uint2*)&ybf[(size_t)(r0 + ty * 4 + i) * 32 + tx * 2] = o;
        }
    }
}

// ---------------- K5: hop1 gather (+ tail blocks: rinv, out+=Cc) ----------------

__global__ __launch_bounds__(256) void k_gather6t(const uint4* __restrict__ ybf4,
                                                  const int* __restrict__ csr_s,
                                                  const int* __restrict__ off,
                                                  const int* __restrict__ degi,
                                                  const float* __restrict__ dinv,
                                                  const float4* __restrict__ b1_4,
                                                  const float4* __restrict__ vv_4,
                                                  float* __restrict__ zp, int ngather,
                                                  const float* __restrict__ cnt,
                                                  const float* __restrict__ Cc,
                                                  float* __restrict__ rinv,
                                                  float* __restrict__ out, int B) {
    int tid = threadIdx.x;
    if ((int)blockIdx.x >= ngather) {
        int i = ((int)blockIdx.x - ngather) * 256 + tid;
        if (i < B) {
            float c = cnt[i]; c = c < 1.f ? 1.f : c;
            rinv[i] = 1.0f / c;
            out[i] += Cc[0];
        }
        return;
    }
    int lane = tid & 7;                       // 8 lanes/node, 16B each
    int v = blockIdx.x * 32 + (tid >> 3);
    float dv = dinv[v];
    int base = off[v], deg = degi[v];
    uint4 uy = ybf4[(size_t)v * 8 + lane];
    float a0 = bf_lo(uy.x), a1 = bf_hi(uy.x), a2 = bf_lo(uy.y), a3 = bf_hi(uy.y);
    float a4 = bf_lo(uy.z), a5 = bf_hi(uy.z), a6 = bf_lo(uy.w), a7 = bf_hi(uy.w);
    const int4* ip = (const int4*)(csr_s + base);   // base is 16B-aligned
    int j = 0;
    for (; j + 8 <= deg; j += 8) {
        int4 sa = ip[(j >> 2) + 0];
        int4 sb = ip[(j >> 2) + 1];
        uint4 u0 = ybf4[(size_t)sa.x * 8 + lane];
        uint4 u1 = ybf4[(size_t)sa.y * 8 + lane];
        uint4 u2 = ybf4[(size_t)sa.z * 8 + lane];
        uint4 u3 = ybf4[(size_t)sa.w * 8 + lane];
        uint4 u4 = ybf4[(size_t)sb.x * 8 + lane];
        uint4 u5 = ybf4[(size_t)sb.y * 8 + lane];
        uint4 u6 = ybf4[(size_t)sb.z * 8 + lane];
        uint4 u7 = ybf4[(size_t)sb.w * 8 + lane];
        a0 += bf_lo(u0.x) + bf_lo(u1.x) + bf_lo(u2.x) + bf_lo(u3.x)
            + bf_lo(u4.x) + bf_lo(u5.x) + bf_lo(u6.x) + bf_lo(u7.x);
        a1 += bf_hi(u0.x) + bf_hi(u1.x) + bf_hi(u2.x) + bf_hi(u3.x)
            + bf_hi(u4.x) + bf_hi(u5.x) + bf_hi(u6.x) + bf_hi(u7.x);
        a2 += bf_lo(u0.y) + bf_lo(u1.y) + bf_lo(u2.y) + bf_lo(u3.y)
            + bf_lo(u4.y) + bf_lo(u5.y) + bf_lo(u6.y) + bf_lo(u7.y);
        a3 += bf_hi(u0.y) + bf_hi(u1.y) + bf_hi(u2.y) + bf_hi(u3.y)
            + bf_hi(u4.y) + bf_hi(u5.y) + bf_hi(u6.y) + bf_hi(u7.y);
        a4 += bf_lo(u0.z) + bf_lo(u1.z) + bf_lo(u2.z) + bf_lo(u3.z)
            + bf_lo(u4.z) + bf_lo(u5.z) + bf_lo(u6.z) + bf_lo(u7.z);
        a5 += bf_hi(u0.z) + bf_hi(u1.z) + bf_hi(u2.z) + bf_hi(u3.z)
            + bf_hi(u4.z) + bf_hi(u5.z) + bf_hi(u6.z) + bf_hi(u7.z);
        a6 += bf_lo(u0.w) + bf_lo(u1.w) + bf_lo(u2.w) + bf_lo(u3.w)
            + bf_lo(u4.w) + bf_lo(u5.w) + bf_lo(u6.w) + bf_lo(u7.w);
        a7 += bf_hi(u0.w) + bf_hi(u1.w) + bf_hi(u2.w) + bf_hi(u3.w)
            + bf_hi(u4.w) + bf_hi(u5.w) + bf_hi(u6.w) + bf_hi(u7.w);
    }
    for (; j + 4 <= deg; j += 4) {
        int4 s4 = ip[j >> 2];
        uint4 u0 = ybf4[(size_t)s4.x * 8 + lane];
        uint4 u1 = ybf4[(size_t)s4.y * 8 + lane];
        uint4 u2 = ybf4[(size_t)s4.z * 8 + lane];
        uint4 u3 = ybf4[(size_t)s4.w * 8 + lane];
        a0 += bf_lo(u0.x) + bf_lo(u1.x) + bf_lo(u2.x) + bf_lo(u3.x);
        a1 += bf_hi(u0.x) + bf_hi(u1.x) + bf_hi(u2.x) + bf_hi(u3.x);
        a2 += bf_lo(u0.y) + bf_lo(u1.y) + bf_lo(u2.y) + bf_lo(u3.y);
        a3 += bf_hi(u0.y) + bf_hi(u1.y) + bf_hi(u2.y) + bf_hi(u3.y);
        a4 += bf_lo(u0.z) + bf_lo(u1.z) + bf_lo(u2.z) + bf_lo(u3.z);
        a5 += bf_hi(u0.z) + bf_hi(u1.z) + bf_hi(u2.z) + bf_hi(u3.z);
        a6 += bf_lo(u0.w) + bf_lo(u1.w) + bf_lo(u2.w) + bf_lo(u3.w);
        a7 += bf_hi(u0.w) + bf_hi(u1.w) + bf_hi(u2.w) + bf_hi(u3.w);
    }
    for (; j < deg; j++) {
        uint4 u = ybf4[(size_t)csr_s[base + j] * 8 + lane];
        a0 += bf_lo(u.x); a1 += bf_hi(u.x); a2 += bf_lo(u.y); a3 += bf_hi(u.y);
        a4 += bf_lo(u.z); a5 += bf_hi(u.z); a6 += bf_lo(u.w); a7 += bf_hi(u.w);
    }
    float4 b0 = b1_4[lane * 2 + 0], b1v = b1_4[lane * 2 + 1];
    float4 v0 = vv_4[lane * 2 + 0], v1v = vv_4[lane * 2 + 1];
    float p = fmaxf(dv * a0 + b0.x, 0.f) * v0.x
            + fmaxf(dv * a1 + b0.y, 0.f) * v0.y
            + fmaxf(dv * a2 + b0.z, 0.f) * v0.z
            + fmaxf(dv * a3 + b0.w, 0.f) * v0.w
            + fmaxf(dv * a4 + b1v.x, 0.f) * v1v.x
            + fmaxf(dv * a5 + b1v.y, 0.f) * v1v.y
            + fmaxf(dv * a6 + b1v.z, 0.f) * v1v.z
            + fmaxf(dv * a7 + b1v.w, 0.f) * v1v.w;
    p += __shfl_xor(p, 1);
    p += __shfl_xor(p, 2);
    p += __shfl_xor(p, 4);
    if (lane == 0) zp[v] = dv * p;
}

// ---------------- K6: hop2, int4 indices, scaled atomic into d_out ----------------

__global__ __launch_bounds__(256) void k_pass2f(const float* __restrict__ zp,
                                                const int* __restrict__ csr_s,
                                                const int* __restrict__ off,
                                                const int* __restrict__ degi,
                                                const float* __restrict__ dinv,
                                                const int* __restrict__ batch,
                                                const float* __restrict__ rinv,
                                                float* __restrict__ out) {
    int v = blockIdx.x * 256 + threadIdx.x;
    float dv = dinv[v];
    int base = off[v], ce = degi[v];
    float acc = zp[v];
    const int4* ip = (const int4*)(csr_s + base);
    int j = 0;
    for (; j + 4 <= ce; j += 4) {
        int4 s4 = ip[j >> 2];
        acc += zp[s4.x] + zp[s4.y] + zp[s4.z] + zp[s4.w];
    }
    for (; j < ce; j++) acc += zp[csr_s[base + j]];
    int g = batch[v];
    atomicAdd(&out[g], dv * acc * rinv[g]);
}

// ---------------- launcher ----------------

extern "C" void kernel_launch(void* const* d_in, const int* in_sizes, int n_in,
                              void* d_out, int out_size, void* d_ws, size_t ws_size,
                              hipStream_t stream) {
    const float* smiles  = (const float*)d_in[0];
    const float* x       = (const float*)d_in[1];
    const int*   ei      = (const int*)d_in[2];
    const int*   batch   = (const int*)d_in[3];
    const float* emb_W1  = (const float*)d_in[4];
    const float* emb_b1  = (const float*)d_in[5];
    const float* emb_W2  = (const float*)d_in[6];
    const float* emb_b2  = (const float*)d_in[7];
    const float* conv1_W = (const float*)d_in[8];
    const float* conv1_b = (const float*)d_in[9];
    const float* conv2_W = (const float*)d_in[10];
    const float* conv2_b = (const float*)d_in[11];
    const float* gcn_fc_W = (const float*)d_in[12];
    const float* gcn_fc_b = (const float*)d_in[13];
    const float* fc1_W   = (const float*)d_in[14];
    const float* fc1_b   = (const float*)d_in[15];
    const float* fcf_W   = (const float*)d_in[16];
    const float* fcf_b   = (const float*)d_in[17];

    const int N = in_sizes[3];          // 131072
    const int E = in_sizes[2] / 2;      // 2097152
    const int B = in_sizes[0] / 768;    // 4096

    char* w = (char*)d_ws;
    float* cnt    = (float*)w;                  w += (size_t)B * 4;
    float* rinv   = (float*)w;                  w += (size_t)B * 4;
    int*   bcur   = (int*)w;                    w += 512 * 4;
    int*   H      = (int*)w;                    w += (size_t)NPB * NBUCK * 4;
    int*   degi   = (int*)w;                    w += (size_t)N * 4;
    float* dinv   = (float*)w;                  w += (size_t)N * 4;
    int*   off    = (int*)w;                    w += (size_t)N * 4;
    float* zp     = (float*)w;                  w += (size_t)N * 4;
    float* vv     = (float*)w;                  w += 64 * 4;
    float* uu     = (float*)w;                  w += 1024 * 4;
    float* Cc     = (float*)w;                  w += 32 * 4;
    uint*  packed = (uint*)w;                   w += (size_t)NBUCK * BCAP * 4;
    int*   csr_s  = (int*)w;                    w += (size_t)NBUCK * CCAP * 4;
    uint*  Abf    = (uint*)w;                   w += (size_t)B * 384 * 4;
    uint*  Btbf   = (uint*)w;                   w += (size_t)1024 * 384 * 4;
    uint*  ybf    = (uint*)w;                   /* N*32 uints */

    const int* esrc = ei;
    const int* edst = ei + E;

    const int NT = (B + 255) / 256;     // 16 tail blocks
    const int NGT = N / 32;             // 4096 gather blocks

    k1_fused<<<HIST_BLOCKS + CVTA_BLOCKS + CVTB_BLOCKS + 1 + NT, 256, 0, stream>>>(
        edst, H, E, (const float2*)smiles, Abf, B * 384, emb_W1, Btbf,
        fc1_W, fc1_b, fcf_W, fcf_b, gcn_fc_W, gcn_fc_b,
        conv2_W, conv2_b, emb_W2, emb_b2, vv, uu, Cc, cnt, (float*)d_out, B);
    kp_base<<<NBUCK, 256, 0, stream>>>(H, bcur);
    k_scatter_emb<<<NPB + EMB_BLOCKS, 256, 0, stream>>>(
        esrc, edst, H, packed, E, Abf, Btbf, emb_b1, uu, (float*)d_out);
    k_build_gemm<<<NBUCK, 256, 0, stream>>>(packed, bcur, batch, degi, dinv, off, csr_s,
                                            cnt, x, conv1_W, ybf);
    k_gather6t<<<NGT + NT, 256, 0, stream>>>((const uint4*)ybf, csr_s, off, degi, dinv,
                                             (const float4*)conv1_b, (const float4*)vv, zp,
                                             NGT, cnt, Cc, rinv, (float*)d_out, B);
    k_pass2f<<<N / 256, 256, 0, stream>>>(zp, csr_s, off, degi, dinv, batch, rinv, (float*)d_out);
}

// Round 15
// 183.001 us; speedup vs baseline: 1.1496x; 1.1496x over previous
//
#include <hip/hip_runtime.h>

typedef unsigned int uint;
typedef __attribute__((ext_vector_type(8))) short short8;
typedef __attribute__((ext_vector_type(4))) float f32x4;

#define NBUCK 512
#define BCAP  4608          // packed per-bucket capacity (mean 4096 + 8 sigma)
#define CCAP  5632          // csr per-bucket capacity (BCAP + align pad slack)
#define NPB   512           // partition blocks
#define PCHUNK 4096         // edges per partition block

// ---------------- bf16 helpers ----------------

__device__ __forceinline__ uint pack_bf2(float a, float b) {
    uint ua = __float_as_uint(a), ub = __float_as_uint(b);
    ua = (ua + 0x7FFFu + ((ua >> 16) & 1u)) >> 16;        // RNE to bf16
    ub = (ub + 0x7FFFu + ((ub >> 16) & 1u)) >> 16;
    return ua | (ub << 16);
}
__device__ __forceinline__ float bf_lo(uint u) { return __uint_as_float(u << 16); }
__device__ __forceinline__ float bf_hi(uint u) { return __uint_as_float(u & 0xFFFF0000u); }

// ---------------- K1: hist | cvtA | cvtB | precompute | zero(out,cnt) ----------------

#define HIST_BLOCKS NPB
#define CVTA_BLOCKS 3072
#define CVTB_BLOCKS 192

__global__ __launch_bounds__(256) void k1_fused(const int* __restrict__ dst,
                                                int* __restrict__ H, int E,
                                                const float2* __restrict__ smiles2,
                                                uint* __restrict__ Abf, int n2,
                                                const float* __restrict__ emb_W1,
                                                uint* __restrict__ Btbf,
                                                const float* __restrict__ fc1_W,
                                                const float* __restrict__ fc1_b,
                                                const float* __restrict__ fcf_W,
                                                const float* __restrict__ fcf_b,
                                                const float* __restrict__ gcn_fc_W,
                                                const float* __restrict__ gcn_fc_b,
                                                const float* __restrict__ conv2_W,
                                                const float* __restrict__ conv2_b,
                                                const float* __restrict__ emb_W2,
                                                const float* __restrict__ emb_b2,
                                                float* __restrict__ vv,
                                                float* __restrict__ uu,
                                                float* __restrict__ Cc,
                                                float* __restrict__ cnt,
                                                float* __restrict__ out, int B) {
    __shared__ float shbuf[64 * 66];
    int tid = threadIdx.x;
    int bid = blockIdx.x;
    if (bid < HIST_BLOCKS) {
        int* lh = (int*)shbuf;
        int e0 = bid * PCHUNK, e1 = min(e0 + PCHUNK, E);
        lh[tid] = 0; lh[tid + 256] = 0;
        __syncthreads();
        for (int e = e0 + tid; e < e1; e += 256)
            atomicAdd(&lh[dst[e] >> 8], 1);
        __syncthreads();
        H[bid * NBUCK + tid] = lh[tid];
        H[bid * NBUCK + tid + 256] = lh[tid + 256];
    } else if (bid < HIST_BLOCKS + CVTA_BLOCKS) {
        int i = (bid - HIST_BLOCKS) * 512 + tid;
        if (i < n2) { float2 vx = smiles2[i]; Abf[i] = pack_bf2(vx.x, vx.y); }
        i += 256;
        if (i < n2) { float2 vx = smiles2[i]; Abf[i] = pack_bf2(vx.x, vx.y); }
    } else if (bid < HIST_BLOCKS + CVTA_BLOCKS + CVTB_BLOCKS) {
        int bb = bid - HIST_BLOCKS - CVTA_BLOCKS;
        int k0 = (bb % 12) * 64, n0 = (bb / 12) * 64;
        float (*t)[65] = (float(*)[65])shbuf;
        int r = tid >> 2, cg = (tid & 3) * 16;
#pragma unroll
        for (int i = 0; i < 16; i++)
            t[r][cg + i] = emb_W1[(size_t)(k0 + r) * 1024 + n0 + cg + i];
        __syncthreads();
        int n = tid >> 2;
#pragma unroll
        for (int i = 0; i < 8; i++) {
            int u = (tid & 3) * 8 + i;
            Btbf[(size_t)(n0 + n) * 384 + (k0 >> 1) + u] = pack_bf2(t[2 * u][n], t[2 * u + 1][n]);
        }
    } else if (bid == HIST_BLOCKS + CVTA_BLOCKS + CVTB_BLOCKS) {
        float* t1s = shbuf;
        float* t2s = shbuf + 128;
        if (tid < 128) {
            float s = 0;
            for (int j = 0; j < 64; j++) s += fc1_W[tid * 64 + j] * fcf_W[j];
            t1s[tid] = s;
        }
        __syncthreads();
        if (tid < 128) {
            float s = 0;
            for (int m = 0; m < 64; m++) s += gcn_fc_W[tid * 64 + m] * t1s[64 + m];
            t2s[tid] = s;
        }
        __syncthreads();
        if (tid < 64) {
            float s = 0;
            for (int p = 0; p < 128; p++) s += conv2_W[tid * 128 + p] * t2s[p];
            vv[tid] = s;
        }
        for (int jj = tid; jj < 1024; jj += 256) {
            float s = 0;
            for (int k = 0; k < 64; k++) s += emb_W2[jj * 64 + k] * t1s[k];
            uu[jj] = s;
        }
        if (tid == 0) {
            float c = fcf_b[0];
            for (int j = 0; j < 64; j++)  c += fc1_b[j] * fcf_W[j];
            for (int k = 0; k < 64; k++)  c += emb_b2[k] * t1s[k];
            for (int p = 0; p < 128; p++) c += conv2_b[p] * t2s[p];
            for (int m = 0; m < 64; m++)  c += gcn_fc_b[m] * t1s[64 + m];
            Cc[0] = c;
        }
    } else {
        int i = (bid - HIST_BLOCKS - CVTA_BLOCKS - CVTB_BLOCKS - 1) * 256 + tid;
        if (i < B) { cnt[i] = 0.f; out[i] = 0.f; }
    }
}

// ---------------- K2: column exclusive scan -> bases ----------------

__global__ __launch_bounds__(256) void kp_base(int* __restrict__ H, int* __restrict__ bcur) {
    __shared__ int lsum[256];
    int tid = threadIdx.x, b = blockIdx.x;
    int v0 = H[(tid * 2 + 0) * NBUCK + b];
    int v1 = H[(tid * 2 + 1) * NBUCK + b];
    int s = v0 + v1;
    lsum[tid] = s;
    for (int d = 1; d < 256; d <<= 1) {
        __syncthreads();
        int t = (tid >= d) ? lsum[tid - d] : 0;
        __syncthreads();
        lsum[tid] += t;
    }
    int run = b * BCAP + (lsum[tid] - s);
    H[(tid * 2 + 0) * NBUCK + b] = run; run += v0;
    H[(tid * 2 + 1) * NBUCK + b] = run; run += v1;
    if (tid == 255) bcur[b] = lsum[255];    // total edges in bucket
}

// ---------------- K3: ranked scatter (BW) || embedding MFMA GEMM (64x64 tiles, 1024 blocks) ----------------

#define EMB_BLOCKS 1024

__global__ __launch_bounds__(256) void k_scatter_emb(const int* __restrict__ src,
                                                     const int* __restrict__ dst,
                                                     const int* __restrict__ H,
                                                     uint* __restrict__ packed, int E,
                                                     const uint* __restrict__ Abf,
                                                     const uint* __restrict__ Btbf,
                                                     const float* __restrict__ b1,
                                                     const float* __restrict__ uu,
                                                     float* __restrict__ out) {
    __shared__ uint4 shu[1024];     // 16 KB union
    int tid = threadIdx.x;
    int bid = blockIdx.x;
    if (bid < NPB) {
        int* lbase = (int*)shu;
        int* lh = lbase + NBUCK;
        int e0 = bid * PCHUNK, e1 = min(e0 + PCHUNK, E);
        lbase[tid] = H[bid * NBUCK + tid];
        lbase[tid + 256] = H[bid * NBUCK + tid + 256];
        lh[tid] = 0; lh[tid + 256] = 0;
        __syncthreads();
        for (int e = e0 + tid; e < e1; e += 256) {
            int s = src[e], d = dst[e];
            int b = d >> 8;
            int r = atomicAdd(&lh[b], 1);
            int pos = lbase[b] + r;
            if (pos < (b + 1) * BCAP)
                packed[pos] = ((uint)s << 8) | (uint)(d & 255);
        }
    } else {
        int eb = bid - NPB;                 // [0, 1024)
        int r0 = (eb & 63) * 64;            // 64 row tiles
        int n0 = (eb >> 6) * 64;            // 16 col tiles
        uint4 (*As)[8] = (uint4(*)[8])shu;            // 8 KB
        uint4 (*Bs)[8] = (uint4(*)[8])(shu + 512);    // 8 KB
        int wave = tid >> 6, lane = tid & 63;
        int wm = wave & 1, wn = wave >> 1;
        f32x4 acc[2][2] = {};

        for (int kt = 0; kt < 768; kt += 64) {
#pragma unroll
            for (int i = 0; i < 2; i++) {
                int idx = tid * 2 + i;
                int row = idx >> 3, c = idx & 7;
                uint4 a = *(const uint4*)&Abf[(size_t)(r0 + row) * 384 + (kt >> 1) + c * 4];
                As[row][c ^ (row & 7)] = a;
                uint4 bb = *(const uint4*)&Btbf[(size_t)(n0 + row) * 384 + (kt >> 1) + c * 4];
                Bs[row][c ^ (row & 7)] = bb;
            }
            __syncthreads();
            int lr = lane & 15, kg = lane >> 4;
#pragma unroll
            for (int kk = 0; kk < 2; kk++) {
                short8 af[2], bfr[2];
#pragma unroll
                for (int m = 0; m < 2; m++) {
                    int row = wm * 32 + m * 16 + lr;
                    af[m] = *(short8*)&As[row][(kk * 4 + kg) ^ (row & 7)];
                }
#pragma unroll
                for (int n = 0; n < 2; n++) {
                    int col = wn * 32 + n * 16 + lr;
                    bfr[n] = *(short8*)&Bs[col][(kk * 4 + kg) ^ (col & 7)];
                }
#pragma unroll
                for (int m = 0; m < 2; m++)
#pragma unroll
                    for (int n = 0; n < 2; n++)
                        acc[m][n] = __builtin_amdgcn_mfma_f32_16x16x32_bf16(af[m], bfr[n], acc[m][n], 0, 0, 0);
            }
            __syncthreads();
        }

        int lr = lane & 15, lq = lane >> 4;
#pragma unroll
        for (int m = 0; m < 2; m++) {
#pragma unroll
            for (int j = 0; j < 4; j++) {
                int row = r0 + wm * 32 + m * 16 + lq * 4 + j;
                float p = 0.f;
#pragma unroll
                for (int n = 0; n < 2; n++) {
                    int col = n0 + wn * 32 + n * 16 + lr;
                    p += fmaxf(acc[m][n][j] + b1[col], 0.f) * uu[col];
                }
                p += __shfl_xor(p, 1);
                p += __shfl_xor(p, 2);
                p += __shfl_xor(p, 4);
                p += __shfl_xor(p, 8);
                if (lr == 0) atomicAdd(&out[row], p);
            }
        }
    }
}

// ---------------- K4: per-bucket single-read counting sort -> CSR ----------------

__global__ __launch_bounds__(256) void kb_build_fs(const uint* __restrict__ packed,
                                                   const int* __restrict__ bcur,
                                                   const int* __restrict__ batch,
                                                   int* __restrict__ degi,
                                                   float* __restrict__ dinv,
                                                   int* __restrict__ off,
                                                   int* __restrict__ csr_s,
                                                   float* __restrict__ cnt) {
    int tid = threadIdx.x, b = blockIdx.x;
    __shared__ int lh[256];
    __shared__ int lscan[256];
    __shared__ int loff[256];
    int cntE = min(bcur[b], BCAP);
    const uint* pk = packed + (size_t)b * BCAP;

    uint reg[18];
    ushort rk[18];
    lh[tid] = 0;
    __syncthreads();
#pragma unroll
    for (int t = 0; t < 18; t++) {
        int idx = t * 256 + tid;
        if (idx < cntE) {
            uint u = pk[idx];
            reg[t] = u;
            rk[t] = (ushort)atomicAdd(&lh[u & 255u], 1);
        }
    }
    __syncthreads();
    int dg = lh[tid];
    int dgp = (dg + 3) & ~3;          // pad to int4 alignment
    lscan[tid] = dgp;
    for (int d = 1; d < 256; d <<= 1) {
        __syncthreads();
        int t = (tid >= d) ? lscan[tid - d] : 0;
        __syncthreads();
        lscan[tid] += t;
    }
    int excl = lscan[tid] - dgp;
    int node = (b << 8) + tid;
    degi[node] = dg;
    dinv[node] = rsqrtf((float)dg + 1.0f);
    off[node] = b * CCAP + excl;
    loff[tid] = excl;
    atomicAdd(&cnt[batch[node]], 1.0f);
    __syncthreads();
    int base = b * CCAP;
#pragma unroll
    for (int t = 0; t < 18; t++) {
        int idx = t * 256 + tid;
        if (idx < cntE) {
            uint u = reg[t];
            csr_s[base + loff[u & 255u] + rk[t]] = (int)(u >> 8);
        }
    }
}

// ---------------- K5: y' = dinv*(x@W1) bf16; tail: rinv + out+=Cc ----------------

__global__ __launch_bounds__(256) void k_gemm64i(const float* __restrict__ A,
                                                 const float* __restrict__ W,
                                                 const float* __restrict__ dinv,
                                                 uint* __restrict__ ybf, int ngemm,
                                                 const float* __restrict__ cnt,
                                                 const float* __restrict__ Cc,
                                                 float* __restrict__ out,
                                                 float* __restrict__ rinv, int B) {
    if ((int)blockIdx.x >= ngemm) {
        int i = ((int)blockIdx.x - ngemm) * 256 + threadIdx.x;
        if (i < B) {
            float c = cnt[i]; c = c < 1.f ? 1.f : c;
            rinv[i] = 1.0f / c;
            out[i] += Cc[0];      // kernels serialized: no concurrent writers
        }
        return;
    }
    __shared__ float As[64][65];
    __shared__ float Ws[64][64];
    int tid = threadIdx.x;
    int r0 = blockIdx.x * 64;
    {
        int r = tid >> 2, cg = tid & 3;
        const float4* A4 = (const float4*)(A + (size_t)(r0 + r) * 64);
#pragma unroll
        for (int i = 0; i < 4; i++) {
            float4 a = A4[cg + 4 * i];
            int c = (cg + 4 * i) * 4;
            As[r][c + 0] = a.x; As[r][c + 1] = a.y; As[r][c + 2] = a.z; As[r][c + 3] = a.w;
        }
        const float4* W4 = (const float4*)W;
#pragma unroll
        for (int i = 0; i < 4; i++) {
            int idx = tid + 256 * i;
            float4 w = W4[idx];
            int k = idx >> 4, c = (idx & 15) * 4;
            *(float4*)&Ws[k][c] = w;
        }
    }
    __syncthreads();
    int ty = tid >> 4, tx = tid & 15;
    float acc[4][4] = {};
#pragma unroll 16
    for (int kk = 0; kk < 64; kk++) {
        float4 wv = *(const float4*)&Ws[kk][tx * 4];
        float a0 = As[ty * 4 + 0][kk];
        float a1 = As[ty * 4 + 1][kk];
        float a2 = As[ty * 4 + 2][kk];
        float a3 = As[ty * 4 + 3][kk];
        acc[0][0] += a0 * wv.x; acc[0][1] += a0 * wv.y; acc[0][2] += a0 * wv.z; acc[0][3] += a0 * wv.w;
        acc[1][0] += a1 * wv.x; acc[1][1] += a1 * wv.y; acc[1][2] += a1 * wv.z; acc[1][3] += a1 * wv.w;
        acc[2][0] += a2 * wv.x; acc[2][1] += a2 * wv.y; acc[2][2] += a2 * wv.z; acc[2][3] += a2 * wv.w;
        acc[3][0] += a3 * wv.x; acc[3][1] += a3 * wv.y; acc[3][2] += a3 * wv.z; acc[3][3] += a3 * wv.w;
    }
#pragma unroll
    for (int i = 0; i < 4; i++) {
        float wsc = dinv[r0 + ty * 4 + i];
        uint2 o;
        o.x = pack_bf2(wsc * acc[i][0], wsc * acc[i][1]);
        o.y = pack_bf2(wsc * acc[i][2], wsc * acc[i][3]);
        *(uint2*)&ybf[(size_t)(r0 + ty * 4 + i) * 32 + tx * 2] = o;
    }
}

// ---------------- K6: hop1 gather, 8 lanes/node, uint4 rows, int4 indices, 8-deep ----------------

__global__ __launch_bounds__(256) void k_gather6(const uint4* __restrict__ ybf4,
                                                 const int* __restrict__ csr_s,
                                                 const int* __restrict__ off,
                                                 const int* __restrict__ degi,
                                                 const float* __restrict__ dinv,
                                                 const float4* __restrict__ b1_4,
                                                 const float4* __restrict__ vv_4,
                                                 float* __restrict__ zp) {
    int tid = threadIdx.x;
    int lane = tid & 7;                       // 8 lanes/node, 16B each
    int v = blockIdx.x * 32 + (tid >> 3);
    float dv = dinv[v];
    int base = off[v], deg = degi[v];
    uint4 uy = ybf4[(size_t)v * 8 + lane];
    float a0 = bf_lo(uy.x), a1 = bf_hi(uy.x), a2 = bf_lo(uy.y), a3 = bf_hi(uy.y);
    float a4 = bf_lo(uy.z), a5 = bf_hi(uy.z), a6 = bf_lo(uy.w), a7 = bf_hi(uy.w);
    const int4* ip = (const int4*)(csr_s + base);   // base is 16B-aligned
    int j = 0;
    for (; j + 8 <= deg; j += 8) {
        int4 sa = ip[(j >> 2) + 0];
        int4 sb = ip[(j >> 2) + 1];
        uint4 u0 = ybf4[(size_t)sa.x * 8 + lane];
        uint4 u1 = ybf4[(size_t)sa.y * 8 + lane];
        uint4 u2 = ybf4[(size_t)sa.z * 8 + lane];
        uint4 u3 = ybf4[(size_t)sa.w * 8 + lane];
        uint4 u4 = ybf4[(size_t)sb.x * 8 + lane];
        uint4 u5 = ybf4[(size_t)sb.y * 8 + lane];
        uint4 u6 = ybf4[(size_t)sb.z * 8 + lane];
        uint4 u7 = ybf4[(size_t)sb.w * 8 + lane];
        a0 += bf_lo(u0.x) + bf_lo(u1.x) + bf_lo(u2.x) + bf_lo(u3.x)
            + bf_lo(u4.x) + bf_lo(u5.x) + bf_lo(u6.x) + bf_lo(u7.x);
        a1 += bf_hi(u0.x) + bf_hi(u1.x) + bf_hi(u2.x) + bf_hi(u3.x)
            + bf_hi(u4.x) + bf_hi(u5.x) + bf_hi(u6.x) + bf_hi(u7.x);
        a2 += bf_lo(u0.y) + bf_lo(u1.y) + bf_lo(u2.y) + bf_lo(u3.y)
            + bf_lo(u4.y) + bf_lo(u5.y) + bf_lo(u6.y) + bf_lo(u7.y);
        a3 += bf_hi(u0.y) + bf_hi(u1.y) + bf_hi(u2.y) + bf_hi(u3.y)
            + bf_hi(u4.y) + bf_hi(u5.y) + bf_hi(u6.y) + bf_hi(u7.y);
        a4 += bf_lo(u0.z) + bf_lo(u1.z) + bf_lo(u2.z) + bf_lo(u3.z)
            + bf_lo(u4.z) + bf_lo(u5.z) + bf_lo(u6.z) + bf_lo(u7.z);
        a5 += bf_hi(u0.z) + bf_hi(u1.z) + bf_hi(u2.z) + bf_hi(u3.z)
            + bf_hi(u4.z) + bf_hi(u5.z) + bf_hi(u6.z) + bf_hi(u7.z);
        a6 += bf_lo(u0.w) + bf_lo(u1.w) + bf_lo(u2.w) + bf_lo(u3.w)
            + bf_lo(u4.w) + bf_lo(u5.w) + bf_lo(u6.w) + bf_lo(u7.w);
        a7 += bf_hi(u0.w) + bf_hi(u1.w) + bf_hi(u2.w) + bf_hi(u3.w)
            + bf_hi(u4.w) + bf_hi(u5.w) + bf_hi(u6.w) + bf_hi(u7.w);
    }
    for (; j + 4 <= deg; j += 4) {
        int4 s4 = ip[j >> 2];
        uint4 u0 = ybf4[(size_t)s4.x * 8 + lane];
        uint4 u1 = ybf4[(size_t)s4.y * 8 + lane];
        uint4 u2 = ybf4[(size_t)s4.z * 8 + lane];
        uint4 u3 = ybf4[(size_t)s4.w * 8 + lane];
        a0 += bf_lo(u0.x) + bf_lo(u1.x) + bf_lo(u2.x) + bf_lo(u3.x);
        a1 += bf_hi(u0.x) + bf_hi(u1.x) + bf_hi(u2.x) + bf_hi(u3.x);
        a2 += bf_lo(u0.y) + bf_lo(u1.y) + bf_lo(u2.y) + bf_lo(u3.y);
        a3 += bf_hi(u0.y) + bf_hi(u1.y) + bf_hi(u2.y) + bf_hi(u3.y);
        a4 += bf_lo(u0.z) + bf_lo(u1.z) + bf_lo(u2.z) + bf_lo(u3.z);
        a5 += bf_hi(u0.z) + bf_hi(u1.z) + bf_hi(u2.z) + bf_hi(u3.z);
        a6 += bf_lo(u0.w) + bf_lo(u1.w) + bf_lo(u2.w) + bf_lo(u3.w);
        a7 += bf_hi(u0.w) + bf_hi(u1.w) + bf_hi(u2.w) + bf_hi(u3.w);
    }
    for (; j < deg; j++) {
        uint4 u = ybf4[(size_t)csr_s[base + j] * 8 + lane];
        a0 += bf_lo(u.x); a1 += bf_hi(u.x); a2 += bf_lo(u.y); a3 += bf_hi(u.y);
        a4 += bf_lo(u.z); a5 += bf_hi(u.z); a6 += bf_lo(u.w); a7 += bf_hi(u.w);
    }
    float4 b0 = b1_4[lane * 2 + 0], b1v = b1_4[lane * 2 + 1];
    float4 v0 = vv_4[lane * 2 + 0], v1v = vv_4[lane * 2 + 1];
    float p = fmaxf(dv * a0 + b0.x, 0.f) * v0.x
            + fmaxf(dv * a1 + b0.y, 0.f) * v0.y
            + fmaxf(dv * a2 + b0.z, 0.f) * v0.z
            + fmaxf(dv * a3 + b0.w, 0.f) * v0.w
            + fmaxf(dv * a4 + b1v.x, 0.f) * v1v.x
            + fmaxf(dv * a5 + b1v.y, 0.f) * v1v.y
            + fmaxf(dv * a6 + b1v.z, 0.f) * v1v.z
            + fmaxf(dv * a7 + b1v.w, 0.f) * v1v.w;
    p += __shfl_xor(p, 1);
    p += __shfl_xor(p, 2);
    p += __shfl_xor(p, 4);
    if (lane == 0) zp[v] = dv * p;
}

// ---------------- K7: hop2, int4 indices, scaled atomic into d_out ----------------

__global__ __launch_bounds__(256) void k_pass2f(const float* __restrict__ zp,
                                                const int* __restrict__ csr_s,
                                                const int* __restrict__ off,
                                                const int* __restrict__ degi,
                                                const float* __restrict__ dinv,
                                                const int* __restrict__ batch,
                                                const float* __restrict__ rinv,
                                                float* __restrict__ out) {
    int v = blockIdx.x * 256 + threadIdx.x;
    float dv = dinv[v];
    int base = off[v], ce = degi[v];
    float acc = zp[v];
    const int4* ip = (const int4*)(csr_s + base);
    int j = 0;
    for (; j + 4 <= ce; j += 4) {
        int4 s4 = ip[j >> 2];
        acc += zp[s4.x] + zp[s4.y] + zp[s4.z] + zp[s4.w];
    }
    for (; j < ce; j++) acc += zp[csr_s[base + j]];
    int g = batch[v];
    atomicAdd(&out[g], dv * acc * rinv[g]);
}

// ---------------- launcher ----------------

extern "C" void kernel_launch(void* const* d_in, const int* in_sizes, int n_in,
                              void* d_out, int out_size, void* d_ws, size_t ws_size,
                              hipStream_t stream) {
    const float* smiles  = (const float*)d_in[0];
    const float* x       = (const float*)d_in[1];
    const int*   ei      = (const int*)d_in[2];
    const int*   batch   = (const int*)d_in[3];
    const float* emb_W1  = (const float*)d_in[4];
    const float* emb_b1  = (const float*)d_in[5];
    const float* emb_W2  = (const float*)d_in[6];
    const float* emb_b2  = (const float*)d_in[7];
    const float* conv1_W = (const float*)d_in[8];
    const float* conv1_b = (const float*)d_in[9];
    const float* conv2_W = (const float*)d_in[10];
    const float* conv2_b = (const float*)d_in[11];
    const float* gcn_fc_W = (const float*)d_in[12];
    const float* gcn_fc_b = (const float*)d_in[13];
    const float* fc1_W   = (const float*)d_in[14];
    const float* fc1_b   = (const float*)d_in[15];
    const float* fcf_W   = (const float*)d_in[16];
    const float* fcf_b   = (const float*)d_in[17];

    const int N = in_sizes[3];          // 131072
    const int E = in_sizes[2] / 2;      // 2097152
    const int B = in_sizes[0] / 768;    // 4096

    char* w = (char*)d_ws;
    float* cnt    = (float*)w;                  w += (size_t)B * 4;
    float* rinv   = (float*)w;                  w += (size_t)B * 4;
    int*   bcur   = (int*)w;                    w += 512 * 4;
    int*   H      = (int*)w;                    w += (size_t)NPB * NBUCK * 4;
    int*   degi   = (int*)w;                    w += (size_t)N * 4;
    float* dinv   = (float*)w;                  w += (size_t)N * 4;
    int*   off    = (int*)w;                    w += (size_t)N * 4;
    float* zp     = (float*)w;                  w += (size_t)N * 4;
    float* vv     = (float*)w;                  w += 64 * 4;
    float* uu     = (float*)w;                  w += 1024 * 4;
    float* Cc     = (float*)w;                  w += 32 * 4;
    uint*  packed = (uint*)w;                   w += (size_t)NBUCK * BCAP * 4;
    int*   csr_s  = (int*)w;                    w += (size_t)NBUCK * CCAP * 4;
    uint*  Abf    = (uint*)w;                   w += (size_t)B * 384 * 4;
    uint*  Btbf   = (uint*)w;                   w += (size_t)1024 * 384 * 4;
    uint*  ybf    = (uint*)w;                   /* N*32 uints */

    const int* esrc = ei;
    const int* edst = ei + E;

    const int NG = N / 64;              // 2048 gemm blocks
    const int NT = (B + 255) / 256;     // 16 tail blocks

    k1_fused<<<HIST_BLOCKS + CVTA_BLOCKS + CVTB_BLOCKS + 1 + NT, 256, 0, stream>>>(
        edst, H, E, (const float2*)smiles, Abf, B * 384, emb_W1, Btbf,
        fc1_W, fc1_b, fcf_W, fcf_b, gcn_fc_W, gcn_fc_b,
        conv2_W, conv2_b, emb_W2, emb_b2, vv, uu, Cc, cnt, (float*)d_out, B);
    kp_base<<<NBUCK, 256, 0, stream>>>(H, bcur);
    k_scatter_emb<<<NPB + EMB_BLOCKS, 256, 0, stream>>>(
        esrc, edst, H, packed, E, Abf, Btbf, emb_b1, uu, (float*)d_out);
    kb_build_fs<<<NBUCK, 256, 0, stream>>>(packed, bcur, batch, degi, dinv, off, csr_s, cnt);
    k_gemm64i<<<NG + NT, 256, 0, stream>>>(x, conv1_W, dinv, ybf, NG,
                                           cnt, Cc, (float*)d_out, rinv, B);
    k_gather6<<<N / 32, 256, 0, stream>>>((const uint4*)ybf, csr_s, off, degi, dinv,
                                          (const float4*)conv1_b, (const float4*)vv, zp);
    k_pass2f<<<N / 256, 256, 0, stream>>>(zp, csr_s, off, degi, dinv, batch, rinv, (float*)d_out);
}